// Round 1
// baseline (6621.651 us; speedup 1.0000x reference)
//
#include <hip/hip_runtime.h>
#include <math.h>

#define B_TOT 512
#define T_FR  18
#define NSTEP 16

__device__ __forceinline__ float gelu_f(float x) {
    return 0.5f * x * (1.0f + erff(x * 0.70710678118654752f));
}
__device__ __forceinline__ float sigmoid_f(float x) {
    return 1.0f / (1.0f + expf(-x));
}

// ---------------------------------------------------------------- init ----
// slots0 = broadcast(slot_mu); rmask = mean over the 128 "c" copies of mask_w
__global__ void init_kernel(const float* __restrict__ slot_mu,
                            const float* __restrict__ mask_w,
                            const float* __restrict__ mask_b,
                            float* __restrict__ slots_g,
                            float* __restrict__ rmw, float* __restrict__ rmb) {
    int idx = blockIdx.x * blockDim.x + threadIdx.x;
    const int total = B_TOT * 8 * 128;
    for (int i = idx; i < total; i += gridDim.x * blockDim.x)
        slots_g[i] = slot_mu[i & 1023];
    if (blockIdx.x == 0) {
        for (int i = threadIdx.x; i < 2048; i += blockDim.x) {
            int j = i >> 7, d = i & 127;
            float s = 0.f;
            for (int c = 0; c < 128; ++c) s += mask_w[(c * 16 + j) * 128 + d];
            rmw[i] = s * (1.0f / 128.0f);
        }
        for (int i = threadIdx.x; i < 16; i += blockDim.x) {
            float s = 0.f;
            for (int c = 0; c < 128; ++c) s += mask_b[c * 16 + i];
            rmb[i] = s * (1.0f / 128.0f);
        }
    }
}

// ------------------------------------------------------------- encoder ----
// per-b block: pair -> gelu(conv3x3) -> gelu(conv4x4 s4) -> fs -> kk,vv
__global__ __launch_bounds__(256) void encoder_kernel(
    const float* __restrict__ frames,
    const float* __restrict__ e1w, const float* __restrict__ e1b,
    const float* __restrict__ e2w, const float* __restrict__ e2b,
    const float* __restrict__ tsw, const float* __restrict__ tsb,
    const float* __restrict__ kw,  const float* __restrict__ vw,
    float* __restrict__ kk_g, float* __restrict__ vv_g, int step)
{
    const int b = blockIdx.x;
    const int tid = threadIdx.x;
    __shared__ __align__(16) float s_pair[2 * 256];
    __shared__ __align__(16) float s_e1w[128 * 18];
    __shared__ float s_e1b[128];
    __shared__ __align__(16) float s_f1[32 * 256];   // chunk; aliased as f2T after
    __shared__ __align__(16) float s_fs[16 * 128];

    const float* f0 = frames + ((size_t)b * T_FR + step + 1) * 256;
    const float* f1p = frames + ((size_t)b * T_FR + step) * 256;
    s_pair[tid]       = f0[tid];
    s_pair[256 + tid] = f1p[tid];
    for (int i = tid; i < 128 * 18; i += 256) s_e1w[i] = e1w[i];
    if (tid < 128) s_e1b[tid] = e1b[tid];
    __syncthreads();

    // conv1 neighborhood (position = tid), shared across all 128 channels
    const int y = tid >> 4, x = tid & 15;
    float nb0[9], nb1[9];
#pragma unroll
    for (int ky = 0; ky < 3; ++ky)
#pragma unroll
    for (int kx = 0; kx < 3; ++kx) {
        int yy = y + ky - 1, xx = x + kx - 1;
        bool ok = (yy >= 0 && yy < 16 && xx >= 0 && xx < 16);
        nb0[ky * 3 + kx] = ok ? s_pair[yy * 16 + xx] : 0.f;
        nb1[ky * 3 + kx] = ok ? s_pair[256 + yy * 16 + xx] : 0.f;
    }

    const int co = tid >> 1, ph = tid & 1;   // enc2 output mapping
    float acc[8];
#pragma unroll
    for (int i = 0; i < 8; ++i) acc[i] = 0.f;

    for (int ch = 0; ch < 4; ++ch) {
        const int ci0 = ch * 32;
        // feat1 chunk: 32 channels at this thread's position
#pragma unroll 4
        for (int j = 0; j < 32; ++j) {
            const float* w = &s_e1w[(ci0 + j) * 18];
            float a = s_e1b[ci0 + j];
#pragma unroll
            for (int q = 0; q < 9; ++q) a += nb0[q] * w[q] + nb1[q] * w[q + 9];
            s_f1[j * 256 + tid] = gelu_f(a);
        }
        __syncthreads();
        // enc2 accumulate over this ci chunk
        for (int cl = 0; cl < 32; ++cl) {
#pragma unroll
            for (int ky = 0; ky < 4; ++ky) {
                const float4 w4 = *reinterpret_cast<const float4*>(
                    &e2w[((co * 128 + ci0 + cl) * 4 + ky) * 4]);
#pragma unroll
                for (int i = 0; i < 8; ++i) {
                    const int p = ph * 8 + i;
                    const int oy = p >> 2, ox = p & 3;
                    const float4 f4 = *reinterpret_cast<const float4*>(
                        &s_f1[cl * 256 + (4 * oy + ky) * 16 + 4 * ox]);
                    acc[i] += w4.x * f4.x + w4.y * f4.y + w4.z * f4.z + w4.w * f4.w;
                }
            }
        }
        __syncthreads();
    }

    // feat2^T into s_f1 region: f2T[p][co]
    float* s_f2T = s_f1;
    {
        const float bb = e2b[co];
#pragma unroll
        for (int i = 0; i < 8; ++i)
            s_f2T[(ph * 8 + i) * 128 + co] = gelu_f(acc[i] + bb);
    }
    __syncthreads();

    // fs[n][d] = sum_c f2T[n][c]*tsw[d][c] + tsb[d]
    {
        const int d = tid & 127, ng = tid >> 7;
        float a2[8];
#pragma unroll
        for (int i = 0; i < 8; ++i) a2[i] = 0.f;
        for (int c = 0; c < 128; c += 4) {
            const float4 w4 = *reinterpret_cast<const float4*>(&tsw[d * 128 + c]);
#pragma unroll
            for (int i = 0; i < 8; ++i) {
                const float4 f4 = *reinterpret_cast<const float4*>(
                    &s_f2T[(ng * 8 + i) * 128 + c]);
                a2[i] += w4.x * f4.x + w4.y * f4.y + w4.z * f4.z + w4.w * f4.w;
            }
        }
        const float tb = tsb[d];
#pragma unroll
        for (int i = 0; i < 8; ++i) s_fs[(ng * 8 + i) * 128 + d] = a2[i] + tb;
    }
    __syncthreads();

    // kk[n][j], vv[n][j]
    {
        const int j = tid & 127, ng = tid >> 7;
        float ak[8], av[8];
#pragma unroll
        for (int i = 0; i < 8; ++i) { ak[i] = 0.f; av[i] = 0.f; }
        for (int d = 0; d < 128; d += 4) {
            const float4 wk = *reinterpret_cast<const float4*>(&kw[j * 128 + d]);
            const float4 wv = *reinterpret_cast<const float4*>(&vw[j * 128 + d]);
#pragma unroll
            for (int i = 0; i < 8; ++i) {
                const float4 f4 = *reinterpret_cast<const float4*>(
                    &s_fs[(ng * 8 + i) * 128 + d]);
                ak[i] += wk.x * f4.x + wk.y * f4.y + wk.z * f4.z + wk.w * f4.w;
                av[i] += wv.x * f4.x + wv.y * f4.y + wv.z * f4.z + wv.w * f4.w;
            }
        }
#pragma unroll
        for (int i = 0; i < 8; ++i) {
            const int n = ng * 8 + i;
            kk_g[((size_t)b * 16 + n) * 128 + j] = ak[i];
            vv_g[((size_t)b * 16 + n) * 128 + j] = av[i];
        }
    }
}

// ---------------------------------------------------- slot update + decode ----
__global__ __launch_bounds__(256) void slot_update_kernel(
    const float* __restrict__ frames,
    const float* __restrict__ qw,
    const float* __restrict__ wih, const float* __restrict__ whh,
    const float* __restrict__ bih, const float* __restrict__ bhh,
    const float* __restrict__ m1w, const float* __restrict__ m1b,
    const float* __restrict__ m2w, const float* __restrict__ m2b,
    const float* __restrict__ upw, const float* __restrict__ upb,
    const float* __restrict__ r1w, const float* __restrict__ r1b,
    const float* __restrict__ r2w, const float* __restrict__ r2b,
    const float* __restrict__ rmw, const float* __restrict__ rmb,
    float* __restrict__ slots_g,
    const float* __restrict__ kk_g, const float* __restrict__ vv_g,
    float* __restrict__ out, int step)
{
    const int b = blockIdx.x, tid = threadIdx.x;
    __shared__ __align__(16) float s_slots[1024];
    __shared__ __align__(16) float s_kk[2048];
    __shared__ __align__(16) float s_vv[2048];
    __shared__ __align__(16) float s_qq[1024];    // qq, then upd (GRU x-input)
    __shared__ float s_attn[128];
    __shared__ __align__(16) float s_pool[6144];  // gi+gh; later m1/mot/ml/masks/r1
    __shared__ __align__(16) float s_img[256];
    __shared__ __align__(16) float s_warp[256];

#pragma unroll
    for (int i = 0; i < 4; ++i)
        s_slots[tid + 256 * i] = slots_g[(size_t)b * 1024 + tid + 256 * i];
#pragma unroll
    for (int i = 0; i < 8; ++i) {
        s_kk[tid + 256 * i] = kk_g[(size_t)b * 2048 + tid + 256 * i];
        s_vv[tid + 256 * i] = vv_g[(size_t)b * 2048 + tid + 256 * i];
    }
    s_img[tid] = frames[((size_t)b * T_FR + step + 1) * 256 + tid];
    __syncthreads();

    const float rscale = 0.08838834764831845f;  // 1/sqrt(128)
    float* s_gi = s_pool;
    float* s_gh = s_pool + 3072;

    for (int iter = 0; iter < 3; ++iter) {
        // qq[k][j] = slots[k]·qw[j]
        {
            const int j = tid & 127, kb = tid >> 7;
            float aq[4] = {0.f, 0.f, 0.f, 0.f};
            for (int d = 0; d < 128; d += 4) {
                const float4 w4 = *reinterpret_cast<const float4*>(&qw[j * 128 + d]);
#pragma unroll
                for (int i = 0; i < 4; ++i) {
                    const float4 s4 = *reinterpret_cast<const float4*>(
                        &s_slots[(kb + 2 * i) * 128 + d]);
                    aq[i] += w4.x * s4.x + w4.y * s4.y + w4.z * s4.z + w4.w * s4.w;
                }
            }
#pragma unroll
            for (int i = 0; i < 4; ++i) s_qq[(kb + 2 * i) * 128 + j] = aq[i];
        }
        __syncthreads();
        // logits
        if (tid < 128) {
            const int k = tid >> 4, n = tid & 15;
            float a = 0.f;
            for (int j = 0; j < 128; j += 4) {
                const float4 q4 = *reinterpret_cast<const float4*>(&s_qq[k * 128 + j]);
                const float4 k4 = *reinterpret_cast<const float4*>(&s_kk[n * 128 + j]);
                a += q4.x * k4.x + q4.y * k4.y + q4.z * k4.z + q4.w * k4.w;
            }
            s_attn[k * 16 + n] = a * rscale;
        }
        __syncthreads();
        // softmax over slots k, per n
        if (tid < 16) {
            const int n = tid;
            float m = -1e30f;
#pragma unroll
            for (int k = 0; k < 8; ++k) m = fmaxf(m, s_attn[k * 16 + n]);
            float e[8], ssum = 0.f;
#pragma unroll
            for (int k = 0; k < 8; ++k) { e[k] = expf(s_attn[k * 16 + n] - m); ssum += e[k]; }
            const float inv = 1.f / ssum;
#pragma unroll
            for (int k = 0; k < 8; ++k) s_attn[k * 16 + n] = e[k] * inv;
        }
        __syncthreads();
        // upd[k][d] into s_qq
#pragma unroll
        for (int i = 0; i < 4; ++i) {
            const int o = tid + 256 * i;
            const int d = o & 127, k = o >> 7;
            float a = 0.f;
#pragma unroll
            for (int n = 0; n < 16; ++n) a += s_attn[k * 16 + n] * s_vv[n * 128 + d];
            s_qq[o] = a;
        }
        __syncthreads();
        // GRU: gi = upd@Wih^T + bih ; gh = slots@Whh^T + bhh
        for (int pass = 0; pass < 2; ++pass) {
            const int j = tid + pass * 256;
            if (j < 384) {
                float ai[8], ah[8];
#pragma unroll
                for (int k = 0; k < 8; ++k) { ai[k] = 0.f; ah[k] = 0.f; }
                for (int d = 0; d < 128; d += 4) {
                    const float4 wi = *reinterpret_cast<const float4*>(&wih[j * 128 + d]);
                    const float4 wh = *reinterpret_cast<const float4*>(&whh[j * 128 + d]);
#pragma unroll
                    for (int k = 0; k < 8; ++k) {
                        const float4 u4 = *reinterpret_cast<const float4*>(&s_qq[k * 128 + d]);
                        const float4 h4 = *reinterpret_cast<const float4*>(&s_slots[k * 128 + d]);
                        ai[k] += wi.x * u4.x + wi.y * u4.y + wi.z * u4.z + wi.w * u4.w;
                        ah[k] += wh.x * h4.x + wh.y * h4.y + wh.z * h4.z + wh.w * h4.w;
                    }
                }
                const float bi = bih[j], bh = bhh[j];
#pragma unroll
                for (int k = 0; k < 8; ++k) {
                    s_gi[k * 384 + j] = ai[k] + bi;
                    s_gh[k * 384 + j] = ah[k] + bh;
                }
            }
        }
        __syncthreads();
        // combine
#pragma unroll
        for (int i = 0; i < 4; ++i) {
            const int o = tid + 256 * i;
            const int jc = o & 127, k = o >> 7;
            const float ir = s_gi[k * 384 + jc], iz = s_gi[k * 384 + 128 + jc],
                        inn = s_gi[k * 384 + 256 + jc];
            const float hr = s_gh[k * 384 + jc], hz = s_gh[k * 384 + 128 + jc],
                        hn = s_gh[k * 384 + 256 + jc];
            const float r = sigmoid_f(ir + hr);
            const float z = sigmoid_f(iz + hz);
            const float nn = tanhf(inn + r * hn);
            s_slots[o] = (1.f - z) * nn + z * s_slots[o];
        }
        __syncthreads();
    }

    // persist slots for next step
#pragma unroll
    for (int i = 0; i < 4; ++i)
        slots_g[(size_t)b * 1024 + tid + 256 * i] = s_slots[tid + 256 * i];

    // -------- phase B: motion / ml / masks (pool reuse) --------
    float* s_m1 = s_pool;            // 8*32
    float* s_mot = s_pool + 256;     // 8*2
    float* s_ml = s_pool + 272;      // 8*16
    float* s_masks = s_pool + 512;   // 8*256
    float* s_r1 = s_pool + 2560;     // 8*256
    __syncthreads();
    {
        const int k = tid >> 5, c = tid & 31;
        float a = m1b[c];
        for (int d = 0; d < 128; d += 4) {
            const float4 w4 = *reinterpret_cast<const float4*>(&m1w[c * 128 + d]);
            const float4 s4 = *reinterpret_cast<const float4*>(&s_slots[k * 128 + d]);
            a += w4.x * s4.x + w4.y * s4.y + w4.z * s4.z + w4.w * s4.w;
        }
        s_m1[k * 32 + c] = gelu_f(a);
    }
    __syncthreads();
    if (tid < 16) {
        const int k = tid >> 1, e = tid & 1;
        float a = m2b[e];
#pragma unroll
        for (int c = 0; c < 32; ++c) a += s_m1[k * 32 + c] * m2w[e * 32 + c];
        s_mot[k * 2 + e] = tanhf(a) * 4.0f;
    }
    if (tid >= 64 && tid < 192) {
        const int q = tid - 64;
        const int k = q >> 4, j = q & 15;
        float a = rmb[j];
        for (int d = 0; d < 128; d += 4) {
            const float4 w4 = *reinterpret_cast<const float4*>(&rmw[j * 128 + d]);
            const float4 s4 = *reinterpret_cast<const float4*>(&s_slots[k * 128 + d]);
            a += w4.x * s4.x + w4.y * s4.y + w4.z * s4.z + w4.w * s4.w;
        }
        s_ml[k * 16 + j] = a;
    }
    __syncthreads();
    // transposed-conv mask logits (non-overlapping stride-4 kernel-4)
#pragma unroll
    for (int i = 0; i < 8; ++i) {
        const int o = tid + 256 * i;
        const int ko = o >> 8, yy = (o >> 4) & 15, xx = o & 15;
        const int jj = (yy >> 2) * 4 + (xx >> 2);
        const int wq = (yy & 3) * 4 + (xx & 3);
        float a = upb[ko];
#pragma unroll
        for (int i8 = 0; i8 < 8; ++i8)
            a += s_ml[i8 * 16 + jj] * upw[(i8 * 8 + ko) * 16 + wq];
        s_masks[ko * 256 + yy * 16 + xx] = a;
    }
    __syncthreads();
    // softmax over the 8 masks per pixel
    {
        float m = -1e30f;
#pragma unroll
        for (int k = 0; k < 8; ++k) m = fmaxf(m, s_masks[k * 256 + tid]);
        float e[8], ssum = 0.f;
#pragma unroll
        for (int k = 0; k < 8; ++k) { e[k] = expf(s_masks[k * 256 + tid] - m); ssum += e[k]; }
        const float inv = 1.f / ssum;
#pragma unroll
        for (int k = 0; k < 8; ++k) s_masks[k * 256 + tid] = e[k] * inv;
    }
    __syncthreads();
    // -------- phase C: warp + residual + out --------
    {
        const int yy = tid >> 4, xx = tid & 15;
        const float gxv = -1.0f + (2.0f / 15.0f) * xx;
        const float gyv = -1.0f + (2.0f / 15.0f) * yy;
        float wsum = 0.f;
#pragma unroll
        for (int k = 0; k < 8; ++k) {
            const float fx = s_mot[k * 2 + 0] * 0.125f;
            const float fy = s_mot[k * 2 + 1] * 0.125f;
            const float sgx = fminf(fmaxf(gxv + fx, -1.f), 1.f);
            const float sgy = fminf(fmaxf(gyv + fy, -1.f), 1.f);
            const float ix = (sgx + 1.f) * 7.5f;
            const float iy = (sgy + 1.f) * 7.5f;
            const float x0f = floorf(ix), y0f = floorf(iy);
            const float wx = ix - x0f, wy = iy - y0f;
            const int x0 = (int)x0f, y0 = (int)y0f;
            const int x1 = min(x0 + 1, 15), y1 = min(y0 + 1, 15);
            const float v00 = s_img[y0 * 16 + x0], v01 = s_img[y0 * 16 + x1];
            const float v10 = s_img[y1 * 16 + x0], v11 = s_img[y1 * 16 + x1];
            const float val = (1.f - wy) * ((1.f - wx) * v00 + wx * v01) +
                              wy * ((1.f - wx) * v10 + wx * v11);
            wsum += s_masks[k * 256 + tid] * val;
        }
        s_warp[tid] = wsum;
    }
    __syncthreads();
    // residual convs, 8-channel chunks
    const int yy = tid >> 4, xx = tid & 15;
    float nbz[9];
#pragma unroll
    for (int ky = 0; ky < 3; ++ky)
#pragma unroll
    for (int kx = 0; kx < 3; ++kx) {
        const int y2 = yy + ky - 1, x2 = xx + kx - 1;
        const bool ok = (y2 >= 0 && y2 < 16 && x2 >= 0 && x2 < 16);
        nbz[ky * 3 + kx] = ok ? (s_warp[y2 * 16 + x2] - s_img[y2 * 16 + x2]) : 0.f;
    }
    float racc = 0.f;
    for (int c0 = 0; c0 < 64; c0 += 8) {
#pragma unroll
        for (int cl = 0; cl < 8; ++cl) {
            const int c = c0 + cl;
            float a = r1b[c];
#pragma unroll
            for (int q = 0; q < 9; ++q) a += nbz[q] * r1w[c * 9 + q];
            s_r1[cl * 256 + tid] = gelu_f(a);
        }
        __syncthreads();
#pragma unroll
        for (int cl = 0; cl < 8; ++cl) {
#pragma unroll
            for (int ky = 0; ky < 3; ++ky)
#pragma unroll
            for (int kx = 0; kx < 3; ++kx) {
                const int y2 = yy + ky - 1, x2 = xx + kx - 1;
                if (y2 >= 0 && y2 < 16 && x2 >= 0 && x2 < 16)
                    racc += s_r1[cl * 256 + y2 * 16 + x2] * r2w[(c0 + cl) * 9 + ky * 3 + kx];
            }
        }
        __syncthreads();
    }
    const float resv = tanhf(racc + r2b[0]) * 0.1f;
    const float pred = fminf(fmaxf(s_warp[tid] + resv, 0.f), 1.f);
    out[((size_t)b * NSTEP + step) * 256 + tid] = pred;
}

// -------------------------------------------------------------- launch ----
extern "C" void kernel_launch(void* const* d_in, const int* in_sizes, int n_in,
                              void* d_out, int out_size, void* d_ws, size_t ws_size,
                              hipStream_t stream)
{
    const float* frames = (const float*)d_in[0];
    const float* e1w = (const float*)d_in[1];
    const float* e1b = (const float*)d_in[2];
    const float* e2w = (const float*)d_in[3];
    const float* e2b = (const float*)d_in[4];
    const float* slot_mu = (const float*)d_in[5];
    const float* tsw = (const float*)d_in[6];
    const float* tsb = (const float*)d_in[7];
    const float* qw = (const float*)d_in[8];
    const float* kw = (const float*)d_in[9];
    const float* vw = (const float*)d_in[10];
    const float* wih = (const float*)d_in[11];
    const float* whh = (const float*)d_in[12];
    const float* bih = (const float*)d_in[13];
    const float* bhh = (const float*)d_in[14];
    const float* m1w = (const float*)d_in[15];
    const float* m1b = (const float*)d_in[16];
    const float* m2w = (const float*)d_in[17];
    const float* m2b = (const float*)d_in[18];
    const float* maskw = (const float*)d_in[19];
    const float* maskb = (const float*)d_in[20];
    const float* upw = (const float*)d_in[21];
    const float* upb = (const float*)d_in[22];
    const float* r1w = (const float*)d_in[23];
    const float* r1b = (const float*)d_in[24];
    const float* r2w = (const float*)d_in[25];
    const float* r2b = (const float*)d_in[26];

    float* ws = (float*)d_ws;
    float* slots_g = ws;                        // 512*1024
    float* kk_g = ws + 524288;                  // 512*2048
    float* vv_g = ws + 524288 + 1048576;        // 512*2048
    float* rmw = ws + 524288 + 2097152;         // 16*128
    float* rmb = rmw + 2048;                    // 16

    hipLaunchKernelGGL(init_kernel, dim3(512), dim3(256), 0, stream,
                       slot_mu, maskw, maskb, slots_g, rmw, rmb);
    for (int t = 0; t < NSTEP; ++t) {
        hipLaunchKernelGGL(encoder_kernel, dim3(512), dim3(256), 0, stream,
                           frames, e1w, e1b, e2w, e2b, tsw, tsb, kw, vw,
                           kk_g, vv_g, t);
        hipLaunchKernelGGL(slot_update_kernel, dim3(512), dim3(256), 0, stream,
                           frames, qw, wih, whh, bih, bhh, m1w, m1b, m2w, m2b,
                           upw, upb, r1w, r1b, r2w, r2b, rmw, rmb,
                           slots_g, kk_g, vv_g, (float*)d_out, t);
    }
}